// Round 4
// baseline (84.092 us; speedup 1.0000x reference)
//
#include <hip/hip_runtime.h>

// N=16, C_X=512, C_W=32, groups=16, H=W=out_h=out_w=64, K=3, PAD=1.
constexpr int NB   = 16;
constexpr int CX   = 512;
constexpr int CW   = 32;
constexpr int GRP  = 16;   // CX / CW
constexpr int HW   = 64;
constexpr int PIX  = HW * HW; // 4096

// Block = 256 threads = 512 contiguous pixels (8 oh-rows) of one (n,c).
// Per-pixel weights staged in LDS (9 x 512 floats = 18 KB) so the group loop
// needs no weight VGPR cache and no global weight reloads.
// px=2 per thread; halo pixels via __shfl (edge garbage killed by zeroed
// edge weights); unroll 4 over groups for loads-in-flight.
__global__ __launch_bounds__(256, 6) void agg_kernel(
    const float* __restrict__ in,   // [16][512][64][64]
    const float* __restrict__ wt,   // [16][32][9][4096]
    float* __restrict__ out)        // [16][512][64][64]
{
    __shared__ float wlds[9][512];

    // XCD-chunked swizzle: 4096 blocks, 8 XCDs, bijective since 4096 % 8 == 0.
    int bid = blockIdx.x;
    int wg  = (bid & 7) * (4096 / 8) + (bid >> 3);

    int tid = threadIdx.x;
    int idx = wg * 256 + tid;

    int p  = idx & 31;           // pair index along ow (2 px each)
    int oh = (idx >> 5) & 63;
    int c  = (idx >> 11) & 31;
    int n  = idx >> 16;

    int x   = p * 2;
    int pix = oh * HW + x;

    // Block-level pixel base: this block covers pixels [pix_base, pix_base+512).
    int pix_base = ((wg & 7) * 8) * HW;   // (oh_hi * 8) * 64

    // ---- Stage weights into LDS: wlds[kk][j] = wt[n][c][kk][pix_base + j].
    {
        const float* wp = wt + ((size_t)(n * CW + c) * 9) * PIX + pix_base + tid * 2;
        #pragma unroll
        for (int kk = 0; kk < 9; ++kk) {
            float2 v = *(const float2*)(wp + (size_t)kk * PIX);
            *(float2*)&wlds[kk][tid * 2] = v;
        }
    }
    __syncthreads();

    int lp = tid * 2;  // this thread's local pixel offset in [0,512)

    // Edge masks for out-of-bounds taps (multiply weights by 0/1 at use).
    // Row masks: top row of image (oh==0) kills kk 0..2, bottom kills 6..8.
    float mt = (oh == 0)  ? 0.f : 1.f;
    float mb = (oh == 63) ? 0.f : 1.f;
    float ml = (x == 0)   ? 0.f : 1.f;   // kills w[0/3/6].x
    float mr = (x == 62)  ? 0.f : 1.f;   // kills w[2/5/8].y

    // Clamped row offsets (group-invariant).
    const int r0 = (oh == 0  ? 0  : oh - 1) * HW;
    const int r1 = oh * HW;
    const int r2 = (oh == 63 ? 63 : oh + 1) * HW;

    const float* ibase = in  + (size_t)(n * CX + c) * PIX;
    float*       obase = out + (size_t)(n * CX + c) * PIX + pix;

    #pragma unroll 4
    for (int g = 0; g < GRP; ++g) {
        const float* ip = ibase + (size_t)g * CW * PIX;
        float2 q0 = *(const float2*)(ip + r0 + x);
        float2 q1 = *(const float2*)(ip + r1 + x);
        float2 q2 = *(const float2*)(ip + r2 + x);
        // Halo pixels from neighbor lanes (cross-row garbage zeroed by ml/mr).
        float l0 = __shfl_up(q0.y, 1), h0 = __shfl_down(q0.x, 1);
        float l1 = __shfl_up(q1.y, 1), h1 = __shfl_down(q1.x, 1);
        float l2 = __shfl_up(q2.y, 1), h2 = __shfl_down(q2.x, 1);

        float2 w0 = *(const float2*)&wlds[0][lp];
        float2 w1 = *(const float2*)&wlds[1][lp];
        float2 w2 = *(const float2*)&wlds[2][lp];
        float2 w3 = *(const float2*)&wlds[3][lp];
        float2 w4 = *(const float2*)&wlds[4][lp];
        float2 w5 = *(const float2*)&wlds[5][lp];
        float2 w6 = *(const float2*)&wlds[6][lp];
        float2 w7 = *(const float2*)&wlds[7][lp];
        float2 w8 = *(const float2*)&wlds[8][lp];

        float ax, ay;
        ax = (w0.x * ml) * (l0 * mt);      ay = (w0.y * mt) * q0.x;
        ax = fmaf(w1.x * mt, q0.x, ax);    ay = fmaf(w1.y * mt, q0.y, ay);
        ax = fmaf(w2.x * mt, q0.y, ax);    ay = fmaf(w2.y * mr, h0 * mt, ay);
        ax = fmaf(w3.x * ml, l1,   ax);    ay = fmaf(w3.y, q1.x, ay);
        ax = fmaf(w4.x, q1.x, ax);         ay = fmaf(w4.y, q1.y, ay);
        ax = fmaf(w5.x, q1.y, ax);         ay = fmaf(w5.y * mr, h1, ay);
        ax = fmaf(w6.x * ml, l2 * mb, ax); ay = fmaf(w6.y * mb, q2.x, ay);
        ax = fmaf(w7.x * mb, q2.x, ax);    ay = fmaf(w7.y * mb, q2.y, ay);
        ax = fmaf(w8.x * mb, q2.y, ax);    ay = fmaf(w8.y * mr, h2 * mb, ay);

        *(float2*)(obase + (size_t)g * CW * PIX) = float2{ax, ay};
    }
}

extern "C" void kernel_launch(void* const* d_in, const int* in_sizes, int n_in,
                              void* d_out, int out_size, void* d_ws, size_t ws_size,
                              hipStream_t stream) {
    const float* in = (const float*)d_in[0];   // (16, 512, 64, 64) f32
    const float* wt = (const float*)d_in[1];   // (16, 32, 9, 4096) f32
    float* out = (float*)d_out;                // (16, 512, 64, 64) f32

    const int total_threads = NB * CW * HW * (HW / 2);  // 1,048,576
    const int block = 256;
    const int grid = total_threads / block;             // 4096
    agg_kernel<<<grid, block, 0, stream>>>(in, wt, out);
}